// Round 1
// baseline (27843.268 us; speedup 1.0000x reference)
//
#include <hip/hip_runtime.h>
#include <hip/hip_cooperative_groups.h>
#include <math.h>

namespace cg = cooperative_groups;

#define Bn   128
#define Sn   336
#define INd  64
#define Hn   1024
#define Tn   96
#define G4   4096
#define KCE  34     // enc k-chunks: [x(64) | h(1024)]
#define KCD  65     // dec k-chunks: [ctx(1024) | h(1024) | prev_y | pad]
#define KCQ  32     // attn query k-chunks

typedef __attribute__((ext_vector_type(8))) short short8;
typedef __attribute__((ext_vector_type(4))) float floatx4;
typedef __attribute__((ext_vector_type(4))) unsigned int uintx4;

__device__ __forceinline__ float sigmoidf_(float x){ return 1.0f/(1.0f+expf(-x)); }

__device__ __forceinline__ unsigned short f2bf(float f){
    union { float f; unsigned u; } v; v.f = f;
    unsigned r = v.u + 0x7fffu + ((v.u >> 16) & 1u);
    return (unsigned short)(r >> 16);
}
__device__ __forceinline__ float bflo(unsigned u){ union{unsigned u; float f;} v; v.u = u << 16;        return v.f; }
__device__ __forceinline__ float bfhi(unsigned u){ union{unsigned u; float f;} v; v.u = u & 0xffff0000u; return v.f; }
__device__ __forceinline__ void unpack8v(uintx4 v, float* f){
    f[0]=bflo(v.x); f[1]=bfhi(v.x); f[2]=bflo(v.y); f[3]=bfhi(v.y);
    f[4]=bflo(v.z); f[5]=bfhi(v.z); f[6]=bflo(v.w); f[7]=bfhi(v.w);
}

// ===================== fragment-order packing ==============================
__global__ void pack_encf(const float* __restrict__ Wih, const float* __restrict__ Whh,
                          const float* __restrict__ bih, const float* __restrict__ bhh,
                          unsigned short* __restrict__ Wp, float* __restrict__ bc){
    long n = (long)256*KCE*512;
    for (long idx = (long)blockIdx.x*256 + threadIdx.x; idx < n; idx += (long)gridDim.x*256){
        int j = (int)(idx & 7), l = (int)((idx >> 3) & 63);
        int kc = (int)((idx >> 9) % KCE);
        int s  = (int)(idx / (KCE*512));
        int c = l & 15, kg = l >> 4;
        int k = kc*32 + kg*8 + j;
        int gate = s & 3, unit = (s >> 2)*16 + c;
        int orig = gate*Hn + unit;
        float v = (k < INd) ? Wih[orig*INd + k] : Whh[(size_t)orig*Hn + (k - INd)];
        Wp[idx] = f2bf(v);
    }
    int tid = blockIdx.x*256 + threadIdx.x;
    if (tid < G4){
        int g = (tid >> 4) & 3, u = (tid >> 6)*16 + (tid & 15);
        int orig = g*Hn + u;
        bc[tid] = bih[orig] + bhh[orig];
    }
}

__global__ void pack_decf(const float* __restrict__ Wih, const float* __restrict__ Whh,
                          const float* __restrict__ bih, const float* __restrict__ bhh,
                          unsigned short* __restrict__ Wp, float* __restrict__ bc){
    long n = (long)256*KCD*512;
    for (long idx = (long)blockIdx.x*256 + threadIdx.x; idx < n; idx += (long)gridDim.x*256){
        int j = (int)(idx & 7), l = (int)((idx >> 3) & 63);
        int kc = (int)((idx >> 9) % KCD);
        int s  = (int)(idx / (KCD*512));
        int c = l & 15, kg = l >> 4;
        int k = kc*32 + kg*8 + j;
        int gate = s & 3, unit = (s >> 2)*16 + c;
        int orig = gate*Hn + unit;
        float v;
        if (k < Hn)          v = Wih[(size_t)orig*(Hn+1) + 1 + k];     // ctx
        else if (k < 2*Hn)   v = Whh[(size_t)orig*Hn + (k - Hn)];      // h
        else if (k == 2*Hn)  v = Wih[(size_t)orig*(Hn+1)];             // prev_y
        else                 v = 0.0f;                                  // pad
        Wp[idx] = f2bf(v);
    }
    int tid = blockIdx.x*256 + threadIdx.x;
    if (tid < G4){
        int g = (tid >> 4) & 3, u = (tid >> 6)*16 + (tid & 15);
        int orig = g*Hn + u;
        bc[tid] = bih[orig] + bhh[orig];
    }
}

__global__ void pack_attnf(const float* __restrict__ w, unsigned short* __restrict__ Wp){
    int n = 64*KCQ*512;
    for (int idx = blockIdx.x*256 + threadIdx.x; idx < n; idx += gridDim.x*256){
        int j = idx & 7, l = (idx >> 3) & 63;
        int kc = (idx >> 9) & 31;
        int s  = idx >> 14;
        int nn = s*16 + (l & 15);
        int k = kc*32 + (l >> 4)*8 + j;
        Wp[idx] = f2bf(w[(size_t)nn*Hn + k]);
    }
}

// src A-fragments: [t][rg(8)][kc(2)][lane][8]; row b = rg*16 + (l&15)
__global__ void conv_srcf(const float* __restrict__ s, unsigned short* __restrict__ d){
    int n = Sn*8*2*512;
    for (int idx = blockIdx.x*256 + threadIdx.x; idx < n; idx += gridDim.x*256){
        int j = idx & 7, l = (idx >> 3) & 63;
        int kc = (idx >> 9) & 1, rg = (idx >> 10) & 7, t = idx >> 13;
        int b = rg*16 + (l & 15);
        int k = kc*32 + (l >> 4)*8 + j;
        d[idx] = f2bf(s[((size_t)b*Sn + t)*INd + k]);
    }
}

__global__ void init_ws(unsigned short* __restrict__ hf0, float* __restrict__ cbuf,
                        unsigned short* __restrict__ A0, unsigned short* __restrict__ A1){
    for (int i = blockIdx.x*256 + threadIdx.x; i < 8*KCD*512; i += gridDim.x*256){
        A0[i] = 0; A1[i] = 0;
        if (i < 8*32*512) hf0[i] = 0;
        if (i < Bn*Hn) cbuf[i] = 0.0f;
    }
}

// XCD-aware swizzle: blocks on XCD k own y in [k*8, k*8+8) -> per-XCD weight
// slice (enc ~1.1MB, dec ~2.1MB) stays L2-resident across all steps.
__device__ __forceinline__ void swz(int b, int& x, int& y){
    int xcd = b & 7, li = b >> 3;
    y = xcd*8 + (li & 7);
    x = li >> 3;
}

// fc dot: pred[b] = h[b,:] . fcW  (lane0 of the wave holds the result)
__device__ __forceinline__ float fcdot(const unsigned short* __restrict__ hplain,
                                       const float* __restrict__ fcW, int b, int l){
    const uintx4* hp = (const uintx4*)(hplain + (size_t)b*Hn) + l*2;
    uintx4 h0 = hp[0], h1 = hp[1];
    float hf[16]; unpack8v(h0, hf); unpack8v(h1, hf + 8);
    float p = 0.0f;
    #pragma unroll
    for (int i = 0; i < 16; i++) p = fmaf(hf[i], fcW[l*16 + i], p);
    #pragma unroll
    for (int off = 32; off; off >>= 1) p += __shfl_down(p, off);
    return p;
}

// ===================== persistent encoder: 336 steps, 1 grid sync each =====
// 256 blocks x 256 thr. wave w -> (rgw = w&1, kh = w>>1). Split-K x2 over kh
// with LDS reduce; kh=0 runs the LSTM epilogue. Only cross-block dep is h.
__global__ __launch_bounds__(256, 1)
void enc_loop(const unsigned short* __restrict__ srcfrag,  // [336][8][2][512]
              const unsigned short* __restrict__ Wf,       // [256][KCE][512]
              const float* __restrict__ bc, float* __restrict__ cbuf,
              unsigned short* __restrict__ hf0,            // [8][32][512]
              unsigned short* __restrict__ hf1,
              unsigned short* __restrict__ enco,
              unsigned short* __restrict__ adec0)          // [8][KCD][512]
{
    cg::grid_group grid = cg::this_grid();
    __shared__ float red[2][16][65];
    const int tid = threadIdx.x, l = tid & 63, w = tid >> 6;
    const int rgw = w & 1, kh = w >> 1;
    int x, y; swz(blockIdx.x, x, y);
    const int rg = x*2 + rgw;
    const int m0 = rg*16;
    const unsigned short* Bf = Wf + (size_t)(4*y)*KCE*512 + l*8;

    const int col = l & 15, q = l >> 4;
    const int u = y*16 + col;
    const float bi  = bc[y*64 + col];
    const float bf_ = bc[y*64 + 16 + col];
    const float bg  = bc[y*64 + 32 + col];
    const float bo  = bc[y*64 + 48 + col];
    const int lsh = ((u >> 3) & 3) * 16;

    for (int t = 0; t < Sn; t++){
        const unsigned short* hin = (t & 1) ? hf1 : hf0;
        unsigned short* hout      = (t & 1) ? hf0 : hf1;
        const unsigned short* Ah = hin + (size_t)rg*32*512 + l*8;
        floatx4 acc0={0,0,0,0}, acc1={0,0,0,0}, acc2={0,0,0,0}, acc3={0,0,0,0};

        if (kh == 0){
            const unsigned short* Ax = srcfrag + ((size_t)t*8 + rg)*2*512 + l*8;
            #pragma unroll
            for (int kc = 0; kc < 2; kc++){
                short8 a  = *(const short8*)(Ax + kc*512);
                short8 b0 = *(const short8*)(Bf + (0*KCE + kc)*512);
                short8 b1 = *(const short8*)(Bf + (1*KCE + kc)*512);
                short8 b2 = *(const short8*)(Bf + (2*KCE + kc)*512);
                short8 b3 = *(const short8*)(Bf + (3*KCE + kc)*512);
                acc0 = __builtin_amdgcn_mfma_f32_16x16x32_bf16(a, b0, acc0, 0, 0, 0);
                acc1 = __builtin_amdgcn_mfma_f32_16x16x32_bf16(a, b1, acc1, 0, 0, 0);
                acc2 = __builtin_amdgcn_mfma_f32_16x16x32_bf16(a, b2, acc2, 0, 0, 0);
                acc3 = __builtin_amdgcn_mfma_f32_16x16x32_bf16(a, b3, acc3, 0, 0, 0);
            }
            #pragma unroll 5
            for (int hc = 0; hc < 15; hc++){
                short8 a  = *(const short8*)(Ah + hc*512);
                short8 b0 = *(const short8*)(Bf + (0*KCE + hc + 2)*512);
                short8 b1 = *(const short8*)(Bf + (1*KCE + hc + 2)*512);
                short8 b2 = *(const short8*)(Bf + (2*KCE + hc + 2)*512);
                short8 b3 = *(const short8*)(Bf + (3*KCE + hc + 2)*512);
                acc0 = __builtin_amdgcn_mfma_f32_16x16x32_bf16(a, b0, acc0, 0, 0, 0);
                acc1 = __builtin_amdgcn_mfma_f32_16x16x32_bf16(a, b1, acc1, 0, 0, 0);
                acc2 = __builtin_amdgcn_mfma_f32_16x16x32_bf16(a, b2, acc2, 0, 0, 0);
                acc3 = __builtin_amdgcn_mfma_f32_16x16x32_bf16(a, b3, acc3, 0, 0, 0);
            }
        } else {
            #pragma unroll 5
            for (int hc = 15; hc < 32; hc++){
                short8 a  = *(const short8*)(Ah + hc*512);
                short8 b0 = *(const short8*)(Bf + (0*KCE + hc + 2)*512);
                short8 b1 = *(const short8*)(Bf + (1*KCE + hc + 2)*512);
                short8 b2 = *(const short8*)(Bf + (2*KCE + hc + 2)*512);
                short8 b3 = *(const short8*)(Bf + (3*KCE + hc + 2)*512);
                acc0 = __builtin_amdgcn_mfma_f32_16x16x32_bf16(a, b0, acc0, 0, 0, 0);
                acc1 = __builtin_amdgcn_mfma_f32_16x16x32_bf16(a, b1, acc1, 0, 0, 0);
                acc2 = __builtin_amdgcn_mfma_f32_16x16x32_bf16(a, b2, acc2, 0, 0, 0);
                acc3 = __builtin_amdgcn_mfma_f32_16x16x32_bf16(a, b3, acc3, 0, 0, 0);
            }
            #pragma unroll
            for (int r = 0; r < 4; r++){
                red[rgw][ 0 + r][l] = acc0[r];
                red[rgw][ 4 + r][l] = acc1[r];
                red[rgw][ 8 + r][l] = acc2[r];
                red[rgw][12 + r][l] = acc3[r];
            }
        }
        __syncthreads();
        if (kh == 0){
            #pragma unroll
            for (int r = 0; r < 4; r++){
                acc0[r] += red[rgw][ 0 + r][l];
                acc1[r] += red[rgw][ 4 + r][l];
                acc2[r] += red[rgw][ 8 + r][l];
                acc3[r] += red[rgw][12 + r][l];
            }
            #pragma unroll
            for (int r = 0; r < 4; r++){
                const int m = m0 + q*4 + r;
                float gi = acc0[r] + bi;
                float gf = acc1[r] + bf_;
                float gg = acc2[r] + bg;
                float go = acc3[r] + bo;
                float co = cbuf[(size_t)m*Hn + u];
                float cn = sigmoidf_(gf)*co + sigmoidf_(gi)*tanhf(gg);
                float hv = sigmoidf_(go)*tanhf(cn);
                cbuf[(size_t)m*Hn + u] = cn;
                unsigned short hb = f2bf(hv);
                const int lanep = (q*4 + r) + lsh;
                hout[(((size_t)rg*32 + (u >> 5))*64 + lanep)*8 + (u & 7)] = hb;
                __builtin_nontemporal_store(hb, enco + ((size_t)m*Sn + t)*Hn + u);
                if (t == Sn-1) adec0[(((size_t)rg*KCD + 32 + (u >> 5))*64 + lanep)*8 + (u & 7)] = hb;
            }
        }
        grid.sync();
    }
}

// ===================== persistent decoder: 96 steps, 3 grid syncs each =====
// 256 blocks x 512 thr (8 waves: rgw=w&1, ks=w>>1).
// Phase A: dec-GEMM h-part (kc32..63, split-K x4, acc held in regs) +
//          attnq (ks==1 waves) + pred=fc(h_{d-1}) (x==0, w>=6 waves).
// Phase B: fused online-softmax attention (blocks 0..127, one b each).
// Phase C: ctx-part (kc0..31) + prev_y (kc64, ks==3) + LDS split-K reduce +
//          LSTM epilogue -> h fragments + plain h.
__global__ __launch_bounds__(512, 2)
void dec_loop(unsigned short* __restrict__ A0, unsigned short* __restrict__ A1,
              const unsigned short* __restrict__ Wdec,    // [256][KCD][512]
              const float* __restrict__ bdec, float* __restrict__ cbuf,
              const unsigned short* __restrict__ Watt,    // [64][KCQ][512]
              unsigned short* __restrict__ qbf,           // [128][1024] bf16
              const unsigned short* __restrict__ enco,    // [128][336][1024]
              unsigned short* __restrict__ hplain,        // [128][1024] bf16
              const float* __restrict__ fcW, const float* __restrict__ fcb,
              float* __restrict__ out)
{
    cg::grid_group grid = cg::this_grid();
    __shared__ float smem[8224];   // phase B: ctxl[8192]+mred[8]@8192+lred[8]@8200
                                   // phase C: redc[3][2][16][64] (6144 floats)
    const int tid = threadIdx.x, l = tid & 63, w = tid >> 6;
    const int rgw = w & 1, ks = w >> 1;
    int x, y; swz(blockIdx.x, x, y);
    const int rg = x*2 + rgw, m0 = rg*16;
    const unsigned short* Bf = Wdec + (size_t)(4*y)*KCD*512 + l*8;

    const int col = l & 15, q4 = l >> 4;
    const int u = y*16 + col;
    const float bi  = bdec[y*64 + col];
    const float bf_ = bdec[y*64 + 16 + col];
    const float bg  = bdec[y*64 + 32 + col];
    const float bo  = bdec[y*64 + 48 + col];
    const int lsh = ((u >> 3) & 3) * 16;

    for (int d = 0; d < Tn; d++){
        unsigned short* Ac = (d & 1) ? A1 : A0;
        unsigned short* An = (d & 1) ? A0 : A1;
        const unsigned short* Af = Ac + (size_t)rg*KCD*512 + l*8;

        // ---------------- phase A ----------------
        floatx4 acc0={0,0,0,0}, acc1={0,0,0,0}, acc2={0,0,0,0}, acc3={0,0,0,0};
        {
            const int kc0 = 32 + ks*8;
            #pragma unroll
            for (int kk = 0; kk < 8; kk++){
                const int kc = kc0 + kk;
                short8 a  = *(const short8*)(Af + kc*512);
                short8 b0 = *(const short8*)(Bf + (0*KCD + kc)*512);
                short8 b1 = *(const short8*)(Bf + (1*KCD + kc)*512);
                short8 b2 = *(const short8*)(Bf + (2*KCD + kc)*512);
                short8 b3 = *(const short8*)(Bf + (3*KCD + kc)*512);
                acc0 = __builtin_amdgcn_mfma_f32_16x16x32_bf16(a, b0, acc0, 0, 0, 0);
                acc1 = __builtin_amdgcn_mfma_f32_16x16x32_bf16(a, b1, acc1, 0, 0, 0);
                acc2 = __builtin_amdgcn_mfma_f32_16x16x32_bf16(a, b2, acc2, 0, 0, 0);
                acc3 = __builtin_amdgcn_mfma_f32_16x16x32_bf16(a, b3, acc3, 0, 0, 0);
            }
        }
        if (ks == 1){   // attnq: waves 2,3 -> tile (rg, y), K = h chunks
            const unsigned short* Aq = Ac + ((size_t)rg*KCD + 32)*512 + l*8;
            const unsigned short* Bq = Watt + (size_t)y*KCQ*512 + l*8;
            floatx4 qa = {0,0,0,0};
            #pragma unroll 8
            for (int kc = 0; kc < KCQ; kc++){
                short8 a = *(const short8*)(Aq + kc*512);
                short8 b = *(const short8*)(Bq + kc*512);
                qa = __builtin_amdgcn_mfma_f32_16x16x32_bf16(a, b, qa, 0, 0, 0);
            }
            #pragma unroll
            for (int r = 0; r < 4; r++)
                qbf[(size_t)(m0 + q4*4 + r)*Hn + y*16 + col] = f2bf(qa[r]);
        }
        if (d > 0 && x == 0 && w >= 6){   // pred_{d-1} = fc(h_{d-1})
            const int b = y*2 + (w & 1);
            float p = fcdot(hplain, fcW, b, l);
            if (l == 0){
                float pv = p + fcb[0];
                out[b*Tn + (d-1)] = pv;
                Ac[(((size_t)(b >> 4))*KCD + 64)*512 + (b & 15)*8] = f2bf(pv);
            }
        }
        grid.sync();

        // ---------------- phase B: attention ----------------
        if (blockIdx.x < Bn){
            const int b = blockIdx.x;
            float* ctxl = smem;
            float* mred = smem + 8192;
            float* lred = smem + 8200;
            float qv[16];
            {
                const uintx4* qp = (const uintx4*)(qbf + (size_t)b*Hn) + l*2;
                uintx4 q0 = qp[0], q1 = qp[1];
                unpack8v(q0, qv); unpack8v(q1, qv + 8);
            }
            float mx = -1e30f, lsum = 0.0f;
            float cacc[16];
            #pragma unroll
            for (int i = 0; i < 16; i++) cacc[i] = 0.0f;

            const uintx4* ebase = (const uintx4*)(enco + (size_t)b*Sn*Hn) + l*2;
            for (int s = w; s < Sn; s += 8){
                uintx4 e0 = __builtin_nontemporal_load(ebase + (size_t)s*128);
                uintx4 e1 = __builtin_nontemporal_load(ebase + (size_t)s*128 + 1);
                float ev[16];
                unpack8v(e0, ev); unpack8v(e1, ev + 8);
                float part = 0.0f;
                #pragma unroll
                for (int i = 0; i < 16; i++) part = fmaf(qv[i], ev[i], part);
                #pragma unroll
                for (int off = 32; off; off >>= 1) part += __shfl_down(part, off);
                float e = __shfl(part, 0);
                float mn = fmaxf(mx, e);
                float corr = expf(mx - mn);
                float p = expf(e - mn);
                lsum = lsum*corr + p;
                if (corr != 1.0f){
                    #pragma unroll
                    for (int i = 0; i < 16; i++) cacc[i] *= corr;
                }
                #pragma unroll
                for (int i = 0; i < 16; i++) cacc[i] = fmaf(p, ev[i], cacc[i]);
                mx = mn;
            }
            if (l == 0){ mred[w] = mx; lred[w] = lsum; }
            __syncthreads();
            float M = mred[0];
            #pragma unroll
            for (int k = 1; k < 8; k++) M = fmaxf(M, mred[k]);
            float corr2 = expf(mx - M);
            #pragma unroll
            for (int j = 0; j < 16; j++) ctxl[w*1024 + j*64 + l] = cacc[j]*corr2;
            __syncthreads();
            float L = 0.0f;
            #pragma unroll
            for (int k = 0; k < 8; k++) L += lred[k]*expf(mred[k] - M);
            float invL = 1.0f / L;

            const int u0 = 2*tid;
            float s0 = 0.0f, s1 = 0.0f;
            #pragma unroll
            for (int k = 0; k < 8; k++){
                s0 += ctxl[k*1024 + (u0 & 15)*64 + (u0 >> 4)];
                s1 += ctxl[k*1024 + ((u0+1) & 15)*64 + ((u0+1) >> 4)];
            }
            ushort2 cv; cv.x = f2bf(s0*invL); cv.y = f2bf(s1*invL);
            const int kcw = u0 >> 5;
            const int lanep2 = (b & 15) + ((u0 >> 3) & 3)*16;
            *(ushort2*)(Ac + ((((size_t)(b >> 4))*KCD + kcw)*64 + lanep2)*8 + (u0 & 7)) = cv;
        }
        grid.sync();

        // ---------------- phase C ----------------
        {
            const int kc0 = ks*8;
            #pragma unroll
            for (int kk = 0; kk < 8; kk++){
                const int kc = kc0 + kk;
                short8 a  = *(const short8*)(Af + kc*512);
                short8 b0 = *(const short8*)(Bf + (0*KCD + kc)*512);
                short8 b1 = *(const short8*)(Bf + (1*KCD + kc)*512);
                short8 b2 = *(const short8*)(Bf + (2*KCD + kc)*512);
                short8 b3 = *(const short8*)(Bf + (3*KCD + kc)*512);
                acc0 = __builtin_amdgcn_mfma_f32_16x16x32_bf16(a, b0, acc0, 0, 0, 0);
                acc1 = __builtin_amdgcn_mfma_f32_16x16x32_bf16(a, b1, acc1, 0, 0, 0);
                acc2 = __builtin_amdgcn_mfma_f32_16x16x32_bf16(a, b2, acc2, 0, 0, 0);
                acc3 = __builtin_amdgcn_mfma_f32_16x16x32_bf16(a, b3, acc3, 0, 0, 0);
            }
            if (ks == 3){   // prev_y + pad chunk
                short8 a  = *(const short8*)(Af + 64*512);
                short8 b0 = *(const short8*)(Bf + (0*KCD + 64)*512);
                short8 b1 = *(const short8*)(Bf + (1*KCD + 64)*512);
                short8 b2 = *(const short8*)(Bf + (2*KCD + 64)*512);
                short8 b3 = *(const short8*)(Bf + (3*KCD + 64)*512);
                acc0 = __builtin_amdgcn_mfma_f32_16x16x32_bf16(a, b0, acc0, 0, 0, 0);
                acc1 = __builtin_amdgcn_mfma_f32_16x16x32_bf16(a, b1, acc1, 0, 0, 0);
                acc2 = __builtin_amdgcn_mfma_f32_16x16x32_bf16(a, b2, acc2, 0, 0, 0);
                acc3 = __builtin_amdgcn_mfma_f32_16x16x32_bf16(a, b3, acc3, 0, 0, 0);
            }
        }
        if (ks != 0){
            float* rp = smem + ((ks-1)*2 + rgw)*1024;
            #pragma unroll
            for (int r = 0; r < 4; r++){
                rp[( 0 + r)*64 + l] = acc0[r];
                rp[( 4 + r)*64 + l] = acc1[r];
                rp[( 8 + r)*64 + l] = acc2[r];
                rp[(12 + r)*64 + l] = acc3[r];
            }
        }
        __syncthreads();
        if (ks == 0){
            const float* r0 = smem + rgw*1024;
            const float* r1 = smem + (2 + rgw)*1024;
            const float* r2 = smem + (4 + rgw)*1024;
            #pragma unroll
            for (int r = 0; r < 4; r++){
                acc0[r] += r0[( 0+r)*64 + l] + r1[( 0+r)*64 + l] + r2[( 0+r)*64 + l];
                acc1[r] += r0[( 4+r)*64 + l] + r1[( 4+r)*64 + l] + r2[( 4+r)*64 + l];
                acc2[r] += r0[( 8+r)*64 + l] + r1[( 8+r)*64 + l] + r2[( 8+r)*64 + l];
                acc3[r] += r0[(12+r)*64 + l] + r1[(12+r)*64 + l] + r2[(12+r)*64 + l];
            }
            #pragma unroll
            for (int r = 0; r < 4; r++){
                const int m = m0 + q4*4 + r;
                float gi = acc0[r] + bi;
                float gf = acc1[r] + bf_;
                float gg = acc2[r] + bg;
                float go = acc3[r] + bo;
                float co = cbuf[(size_t)m*Hn + u];
                float cn = sigmoidf_(gf)*co + sigmoidf_(gi)*tanhf(gg);
                float hv = sigmoidf_(go)*tanhf(cn);
                cbuf[(size_t)m*Hn + u] = cn;
                unsigned short hb = f2bf(hv);
                const int lanep = (q4*4 + r) + lsh;
                An[(((size_t)rg*KCD + 32 + (u >> 5))*64 + lanep)*8 + (u & 7)] = hb;
                hplain[(size_t)m*Hn + u] = hb;
            }
        }
        grid.sync();
    }

    // final pred: out[:, Tn-1] = fc(h_{Tn-1})
    if (x == 0 && w >= 6){
        const int b = y*2 + (w & 1);
        float p = fcdot(hplain, fcW, b, l);
        if (l == 0) out[b*Tn + (Tn - 1)] = p + fcb[0];
    }
}

extern "C" void kernel_launch(void* const* d_in, const int* in_sizes, int n_in,
                              void* d_out, int out_size, void* d_ws, size_t ws_size,
                              hipStream_t stream){
    const float* src  = (const float*)d_in[0];
    const float* eWih = (const float*)d_in[1];
    const float* eWhh = (const float*)d_in[2];
    const float* ebih = (const float*)d_in[3];
    const float* ebhh = (const float*)d_in[4];
    const float* dWih = (const float*)d_in[5];
    const float* dWhh = (const float*)d_in[6];
    const float* dbih = (const float*)d_in[7];
    const float* dbhh = (const float*)d_in[8];
    const float* attnW= (const float*)d_in[9];
    const float* fcW  = (const float*)d_in[10];
    const float* fcb  = (const float*)d_in[11];
    float* out = (float*)d_out;

    char* base = (char*)d_ws;
    auto alloc = [&](size_t bytes){ void* p = base; base += (bytes + 255) & ~255ull; return p; };
    unsigned short* Wencf = (unsigned short*)alloc((size_t)256*KCE*512*2);
    float*          benc  = (float*)alloc(G4*4);
    unsigned short* Wdecf = (unsigned short*)alloc((size_t)256*KCD*512*2);
    float*          bdec  = (float*)alloc(G4*4);
    unsigned short* Wattf = (unsigned short*)alloc((size_t)64*KCQ*512*2);
    unsigned short* srcf  = (unsigned short*)alloc((size_t)Sn*8*2*512*2);
    unsigned short* enco  = (unsigned short*)alloc((size_t)Bn*Sn*Hn*2);
    unsigned short* hf0   = (unsigned short*)alloc((size_t)8*32*512*2);
    unsigned short* hf1   = (unsigned short*)alloc((size_t)8*32*512*2);
    float*          cbuf  = (float*)alloc((size_t)Bn*Hn*4);
    unsigned short* A0f   = (unsigned short*)alloc((size_t)8*KCD*512*2);
    unsigned short* A1f   = (unsigned short*)alloc((size_t)8*KCD*512*2);
    unsigned short* qbf   = (unsigned short*)alloc((size_t)Bn*Hn*2);
    unsigned short* hplain= (unsigned short*)alloc((size_t)Bn*Hn*2);

    conv_srcf<<<2048, 256, 0, stream>>>(src, srcf);
    pack_encf<<<4096, 256, 0, stream>>>(eWih, eWhh, ebih, ebhh, Wencf, benc);
    pack_decf<<<8192, 256, 0, stream>>>(dWih, dWhh, dbih, dbhh, Wdecf, bdec);
    pack_attnf<<<1024, 256, 0, stream>>>(attnW, Wattf);
    init_ws<<<1040, 256, 0, stream>>>(hf0, cbuf, A0f, A1f);

    {
        void* ea[] = {(void*)&srcf, (void*)&Wencf, (void*)&benc, (void*)&cbuf,
                      (void*)&hf0, (void*)&hf1, (void*)&enco, (void*)&A0f};
        hipLaunchCooperativeKernel(enc_loop, dim3(256), dim3(256), ea, 0, stream);
    }
    {
        void* da[] = {(void*)&A0f, (void*)&A1f, (void*)&Wdecf, (void*)&bdec, (void*)&cbuf,
                      (void*)&Wattf, (void*)&qbf, (void*)&enco, (void*)&hplain,
                      (void*)&fcW, (void*)&fcb, (void*)&out};
        hipLaunchCooperativeKernel(dec_loop, dim3(256), dim3(512), da, 0, stream);
    }
}

// Round 2
// 10169.131 us; speedup vs baseline: 2.7380x; 2.7380x over previous
//
#include <hip/hip_runtime.h>
#include <math.h>

#define Bn   128
#define Sn   336
#define INd  64
#define Hn   1024
#define Tn   96
#define G4   4096
#define KCE  34     // enc k-chunks: [x(64) | h(1024)]
#define KCD  65     // dec k-chunks: [ctx(1024) | h(1024) | prev_y | pad]
#define KCQ  32     // attn query k-chunks
#define NBLK 256

typedef __attribute__((ext_vector_type(8))) short short8;
typedef __attribute__((ext_vector_type(4))) float floatx4;
typedef __attribute__((ext_vector_type(4))) unsigned int uintx4;
typedef unsigned long long u64t;

__device__ __forceinline__ float sigmoidf_(float x){ return 1.0f/(1.0f+expf(-x)); }

__device__ __forceinline__ unsigned short f2bf(float f){
    union { float f; unsigned u; } v; v.f = f;
    unsigned r = v.u + 0x7fffu + ((v.u >> 16) & 1u);
    return (unsigned short)(r >> 16);
}
__device__ __forceinline__ float bflo(unsigned u){ union{unsigned u; float f;} v; v.u = u << 16;        return v.f; }
__device__ __forceinline__ float bfhi(unsigned u){ union{unsigned u; float f;} v; v.u = u & 0xffff0000u; return v.f; }
__device__ __forceinline__ void unpack8v(uintx4 v, float* f){
    f[0]=bflo(v.x); f[1]=bfhi(v.x); f[2]=bflo(v.y); f[3]=bfhi(v.y);
    f[4]=bflo(v.z); f[5]=bfhi(v.z); f[6]=bflo(v.w); f[7]=bfhi(v.w);
}

// ---- LLC-coherent (agent-scope, L2-bypassing) access helpers -------------
// Cross-block data inside a persistent kernel must not live in the
// non-coherent per-XCD L2s. Loads: agent-scope relaxed atomics (sc0/sc1,
// served by Infinity Cache). Stores: write-through via sc0/sc1 asm.
union Frag16 { u64t q[2]; short8 s8; uintx4 u4; };

__device__ __forceinline__ short8 ld_cg_s8(const unsigned short* p){
    Frag16 r;
    r.q[0] = __hip_atomic_load((const u64t*)p,     __ATOMIC_RELAXED, __HIP_MEMORY_SCOPE_AGENT);
    r.q[1] = __hip_atomic_load((const u64t*)p + 1, __ATOMIC_RELAXED, __HIP_MEMORY_SCOPE_AGENT);
    return r.s8;
}
__device__ __forceinline__ uintx4 ld_cg_u4(const unsigned short* p){
    Frag16 r;
    r.q[0] = __hip_atomic_load((const u64t*)p,     __ATOMIC_RELAXED, __HIP_MEMORY_SCOPE_AGENT);
    r.q[1] = __hip_atomic_load((const u64t*)p + 1, __ATOMIC_RELAXED, __HIP_MEMORY_SCOPE_AGENT);
    return r.u4;
}
__device__ __forceinline__ void st_cg16(unsigned short* p, unsigned short v){
    asm volatile("global_store_short %0, %1, off sc0 sc1" :: "v"(p), "v"((unsigned)v) : "memory");
}
__device__ __forceinline__ void st_cg32(unsigned short* p, unsigned v){
    asm volatile("global_store_dword %0, %1, off sc0 sc1" :: "v"(p), "v"(v) : "memory");
}

// Flush-free grid barrier: all cross-block traffic is LLC-coherent, so the
// barrier needs only vmcnt-drain + one agent-scope counter (no L2 flush —
// this is what made grid.sync() cost ~40us/step).
__device__ __forceinline__ void gbar(unsigned* ctr, unsigned tgt){
    asm volatile("s_waitcnt vmcnt(0)" ::: "memory");
    __syncthreads();
    if (threadIdx.x == 0){
        __hip_atomic_fetch_add(ctr, 1u, __ATOMIC_RELAXED, __HIP_MEMORY_SCOPE_AGENT);
        while (__hip_atomic_load(ctr, __ATOMIC_RELAXED, __HIP_MEMORY_SCOPE_AGENT) < tgt)
            __builtin_amdgcn_s_sleep(2);
    }
    __syncthreads();
}

// ===================== fragment-order packing ==============================
__global__ void pack_encf(const float* __restrict__ Wih, const float* __restrict__ Whh,
                          const float* __restrict__ bih, const float* __restrict__ bhh,
                          unsigned short* __restrict__ Wp, float* __restrict__ bc){
    long n = (long)256*KCE*512;
    for (long idx = (long)blockIdx.x*256 + threadIdx.x; idx < n; idx += (long)gridDim.x*256){
        int j = (int)(idx & 7), l = (int)((idx >> 3) & 63);
        int kc = (int)((idx >> 9) % KCE);
        int s  = (int)(idx / (KCE*512));
        int c = l & 15, kg = l >> 4;
        int k = kc*32 + kg*8 + j;
        int gate = s & 3, unit = (s >> 2)*16 + c;
        int orig = gate*Hn + unit;
        float v = (k < INd) ? Wih[orig*INd + k] : Whh[(size_t)orig*Hn + (k - INd)];
        Wp[idx] = f2bf(v);
    }
    int tid = blockIdx.x*256 + threadIdx.x;
    if (tid < G4){
        int g = (tid >> 4) & 3, u = (tid >> 6)*16 + (tid & 15);
        int orig = g*Hn + u;
        bc[tid] = bih[orig] + bhh[orig];
    }
}

__global__ void pack_decf(const float* __restrict__ Wih, const float* __restrict__ Whh,
                          const float* __restrict__ bih, const float* __restrict__ bhh,
                          unsigned short* __restrict__ Wp, float* __restrict__ bc){
    long n = (long)256*KCD*512;
    for (long idx = (long)blockIdx.x*256 + threadIdx.x; idx < n; idx += (long)gridDim.x*256){
        int j = (int)(idx & 7), l = (int)((idx >> 3) & 63);
        int kc = (int)((idx >> 9) % KCD);
        int s  = (int)(idx / (KCD*512));
        int c = l & 15, kg = l >> 4;
        int k = kc*32 + kg*8 + j;
        int gate = s & 3, unit = (s >> 2)*16 + c;
        int orig = gate*Hn + unit;
        float v;
        if (k < Hn)          v = Wih[(size_t)orig*(Hn+1) + 1 + k];     // ctx
        else if (k < 2*Hn)   v = Whh[(size_t)orig*Hn + (k - Hn)];      // h
        else if (k == 2*Hn)  v = Wih[(size_t)orig*(Hn+1)];             // prev_y
        else                 v = 0.0f;                                  // pad
        Wp[idx] = f2bf(v);
    }
    int tid = blockIdx.x*256 + threadIdx.x;
    if (tid < G4){
        int g = (tid >> 4) & 3, u = (tid >> 6)*16 + (tid & 15);
        int orig = g*Hn + u;
        bc[tid] = bih[orig] + bhh[orig];
    }
}

__global__ void pack_attnf(const float* __restrict__ w, unsigned short* __restrict__ Wp){
    int n = 64*KCQ*512;
    for (int idx = blockIdx.x*256 + threadIdx.x; idx < n; idx += gridDim.x*256){
        int j = idx & 7, l = (idx >> 3) & 63;
        int kc = (idx >> 9) & 31;
        int s  = idx >> 14;
        int nn = s*16 + (l & 15);
        int k = kc*32 + (l >> 4)*8 + j;
        Wp[idx] = f2bf(w[(size_t)nn*Hn + k]);
    }
}

// src A-fragments: [t][rg(8)][kc(2)][lane][8]; row b = rg*16 + (l&15)
__global__ void conv_srcf(const float* __restrict__ s, unsigned short* __restrict__ d){
    int n = Sn*8*2*512;
    for (int idx = blockIdx.x*256 + threadIdx.x; idx < n; idx += gridDim.x*256){
        int j = idx & 7, l = (idx >> 3) & 63;
        int kc = (idx >> 9) & 1, rg = (idx >> 10) & 7, t = idx >> 13;
        int b = rg*16 + (l & 15);
        int k = kc*32 + (l >> 4)*8 + j;
        d[idx] = f2bf(s[((size_t)b*Sn + t)*INd + k]);
    }
}

__global__ void init_ws(unsigned short* __restrict__ hf0, float* __restrict__ cbuf,
                        unsigned short* __restrict__ A0, unsigned short* __restrict__ A1,
                        unsigned* __restrict__ bars){
    int t0 = blockIdx.x*256 + threadIdx.x;
    if (t0 < 4) bars[t0] = 0;
    for (int i = t0; i < 8*KCD*512; i += gridDim.x*256){
        A0[i] = 0; A1[i] = 0;
        if (i < 8*32*512) hf0[i] = 0;
        if (i < Bn*Hn) cbuf[i] = 0.0f;
    }
}

// XCD-aware swizzle: blocks on XCD k own y in [k*8, k*8+8) -> per-XCD weight
// slice (enc ~1.1MB, dec ~2.1MB) stays L2-resident across all steps (no
// flushes with the manual barrier).
__device__ __forceinline__ void swz(int b, int& x, int& y){
    int xcd = b & 7, li = b >> 3;
    y = xcd*8 + (li & 7);
    x = li >> 3;
}

// fc dot: pred[b] = h[b,:] . fcW  (lane0 of the wave holds the result)
__device__ __forceinline__ float fcdot(const unsigned short* __restrict__ hplain,
                                       const float* __restrict__ fcW, int b, int l){
    const unsigned short* hp = hplain + (size_t)b*Hn + l*16;
    uintx4 h0 = ld_cg_u4(hp), h1 = ld_cg_u4(hp + 8);
    float hf[16]; unpack8v(h0, hf); unpack8v(h1, hf + 8);
    float p = 0.0f;
    #pragma unroll
    for (int i = 0; i < 16; i++) p = fmaf(hf[i], fcW[l*16 + i], p);
    #pragma unroll
    for (int off = 32; off; off >>= 1) p += __shfl_down(p, off);
    return p;
}

// ===================== persistent encoder: 336 steps, 1 LLC barrier each ===
__global__ __launch_bounds__(256, 1)
void enc_loop(const unsigned short* __restrict__ srcfrag,  // [336][8][2][512]
              const unsigned short* __restrict__ Wf,       // [256][KCE][512]
              const float* __restrict__ bc, float* __restrict__ cbuf,
              unsigned short* __restrict__ hf0,            // [8][32][512]
              unsigned short* __restrict__ hf1,
              unsigned short* __restrict__ enco,
              unsigned short* __restrict__ adec0,          // [8][KCD][512]
              unsigned* __restrict__ bar)
{
    __shared__ float red[2][16][65];
    const int tid = threadIdx.x, l = tid & 63, w = tid >> 6;
    const int rgw = w & 1, kh = w >> 1;
    int x, y; swz(blockIdx.x, x, y);
    const int rg = x*2 + rgw;
    const int m0 = rg*16;
    const unsigned short* Bf = Wf + (size_t)(4*y)*KCE*512 + l*8;

    const int col = l & 15, q = l >> 4;
    const int u = y*16 + col;
    const float bi  = bc[y*64 + col];
    const float bf_ = bc[y*64 + 16 + col];
    const float bg  = bc[y*64 + 32 + col];
    const float bo  = bc[y*64 + 48 + col];
    const int lsh = ((u >> 3) & 3) * 16;

    unsigned tgt = NBLK;
    for (int t = 0; t < Sn; t++){
        const unsigned short* hin = (t & 1) ? hf1 : hf0;
        unsigned short* hout      = (t & 1) ? hf0 : hf1;
        const unsigned short* Ah = hin + (size_t)rg*32*512 + l*8;
        floatx4 acc0={0,0,0,0}, acc1={0,0,0,0}, acc2={0,0,0,0}, acc3={0,0,0,0};

        if (kh == 0){
            const unsigned short* Ax = srcfrag + ((size_t)t*8 + rg)*2*512 + l*8;
            #pragma unroll
            for (int kc = 0; kc < 2; kc++){
                short8 a  = *(const short8*)(Ax + kc*512);
                short8 b0 = *(const short8*)(Bf + (0*KCE + kc)*512);
                short8 b1 = *(const short8*)(Bf + (1*KCE + kc)*512);
                short8 b2 = *(const short8*)(Bf + (2*KCE + kc)*512);
                short8 b3 = *(const short8*)(Bf + (3*KCE + kc)*512);
                acc0 = __builtin_amdgcn_mfma_f32_16x16x32_bf16(a, b0, acc0, 0, 0, 0);
                acc1 = __builtin_amdgcn_mfma_f32_16x16x32_bf16(a, b1, acc1, 0, 0, 0);
                acc2 = __builtin_amdgcn_mfma_f32_16x16x32_bf16(a, b2, acc2, 0, 0, 0);
                acc3 = __builtin_amdgcn_mfma_f32_16x16x32_bf16(a, b3, acc3, 0, 0, 0);
            }
            #pragma unroll 5
            for (int hc = 0; hc < 15; hc++){
                short8 a  = ld_cg_s8(Ah + hc*512);
                short8 b0 = *(const short8*)(Bf + (0*KCE + hc + 2)*512);
                short8 b1 = *(const short8*)(Bf + (1*KCE + hc + 2)*512);
                short8 b2 = *(const short8*)(Bf + (2*KCE + hc + 2)*512);
                short8 b3 = *(const short8*)(Bf + (3*KCE + hc + 2)*512);
                acc0 = __builtin_amdgcn_mfma_f32_16x16x32_bf16(a, b0, acc0, 0, 0, 0);
                acc1 = __builtin_amdgcn_mfma_f32_16x16x32_bf16(a, b1, acc1, 0, 0, 0);
                acc2 = __builtin_amdgcn_mfma_f32_16x16x32_bf16(a, b2, acc2, 0, 0, 0);
                acc3 = __builtin_amdgcn_mfma_f32_16x16x32_bf16(a, b3, acc3, 0, 0, 0);
            }
        } else {
            #pragma unroll 5
            for (int hc = 15; hc < 32; hc++){
                short8 a  = ld_cg_s8(Ah + hc*512);
                short8 b0 = *(const short8*)(Bf + (0*KCE + hc + 2)*512);
                short8 b1 = *(const short8*)(Bf + (1*KCE + hc + 2)*512);
                short8 b2 = *(const short8*)(Bf + (2*KCE + hc + 2)*512);
                short8 b3 = *(const short8*)(Bf + (3*KCE + hc + 2)*512);
                acc0 = __builtin_amdgcn_mfma_f32_16x16x32_bf16(a, b0, acc0, 0, 0, 0);
                acc1 = __builtin_amdgcn_mfma_f32_16x16x32_bf16(a, b1, acc1, 0, 0, 0);
                acc2 = __builtin_amdgcn_mfma_f32_16x16x32_bf16(a, b2, acc2, 0, 0, 0);
                acc3 = __builtin_amdgcn_mfma_f32_16x16x32_bf16(a, b3, acc3, 0, 0, 0);
            }
            #pragma unroll
            for (int r = 0; r < 4; r++){
                red[rgw][ 0 + r][l] = acc0[r];
                red[rgw][ 4 + r][l] = acc1[r];
                red[rgw][ 8 + r][l] = acc2[r];
                red[rgw][12 + r][l] = acc3[r];
            }
        }
        __syncthreads();
        if (kh == 0){
            #pragma unroll
            for (int r = 0; r < 4; r++){
                acc0[r] += red[rgw][ 0 + r][l];
                acc1[r] += red[rgw][ 4 + r][l];
                acc2[r] += red[rgw][ 8 + r][l];
                acc3[r] += red[rgw][12 + r][l];
            }
            #pragma unroll
            for (int r = 0; r < 4; r++){
                const int m = m0 + q*4 + r;
                float gi = acc0[r] + bi;
                float gf = acc1[r] + bf_;
                float gg = acc2[r] + bg;
                float go = acc3[r] + bo;
                float co = cbuf[(size_t)m*Hn + u];
                float cn = sigmoidf_(gf)*co + sigmoidf_(gi)*tanhf(gg);
                float hv = sigmoidf_(go)*tanhf(cn);
                cbuf[(size_t)m*Hn + u] = cn;
                unsigned short hb = f2bf(hv);
                const int lanep = (q*4 + r) + lsh;
                st_cg16(hout + (((size_t)rg*32 + (u >> 5))*64 + lanep)*8 + (u & 7), hb);
                enco[((size_t)m*Sn + t)*Hn + u] = hb;   // cached; flushed at kernel end
                if (t == Sn-1) adec0[(((size_t)rg*KCD + 32 + (u >> 5))*64 + lanep)*8 + (u & 7)] = hb;
            }
        }
        gbar(bar, tgt); tgt += NBLK;
    }
}

// ===================== persistent decoder: 96 steps, 3 LLC barriers each ===
// 256 blocks x 512 thr (8 waves: rgw=w&1, ks=w>>1).
// Phase A: dec-GEMM h-part (kc32..63, acc held in regs) + attnq (ks==1) +
//          pred=fc(h_{d-1}) (x==0, w>=6).  k-split 10/4/9/9 rebalances the
//          attnq waves' extra 32 MFMAs.
// Phase B: fused online-softmax attention (blocks 0..127; enco via plain
//          cached loads -> L3-resident, read-only during decode).
// Phase C: ctx-part (kc0..31) + prev_y (kc64, ks==3) + LDS split-K reduce +
//          LSTM epilogue -> h fragments + plain h.
__global__ __launch_bounds__(512, 1)
void dec_loop(unsigned short* __restrict__ A0, unsigned short* __restrict__ A1,
              const unsigned short* __restrict__ Wdec,    // [256][KCD][512]
              const float* __restrict__ bdec, float* __restrict__ cbuf,
              const unsigned short* __restrict__ Watt,    // [64][KCQ][512]
              unsigned short* __restrict__ qbf,           // [128][1024] bf16
              const unsigned short* __restrict__ enco,    // [128][336][1024]
              unsigned short* __restrict__ hplain,        // [128][1024] bf16
              const float* __restrict__ fcW, const float* __restrict__ fcb,
              float* __restrict__ out, unsigned* __restrict__ bar)
{
    __shared__ float smem[8224];   // phase B: ctxl[8192]+mred[8]@8192+lred[8]@8200
                                   // phase C: redc[3][2][16][64] (6144 floats)
    const int tid = threadIdx.x, l = tid & 63, w = tid >> 6;
    const int rgw = w & 1, ks = w >> 1;
    int x, y; swz(blockIdx.x, x, y);
    const int rg = x*2 + rgw, m0 = rg*16;
    const unsigned short* Bf = Wdec + (size_t)(4*y)*KCD*512 + l*8;

    const int col = l & 15, q4 = l >> 4;
    const int u = y*16 + col;
    const float bi  = bdec[y*64 + col];
    const float bf_ = bdec[y*64 + 16 + col];
    const float bg  = bdec[y*64 + 32 + col];
    const float bo  = bdec[y*64 + 48 + col];
    const int lsh = ((u >> 3) & 3) * 16;
    const int ka0 = (ks==0) ? 32 : (ks==1) ? 42 : (ks==2) ? 46 : 55;
    const int ka1 = (ks==0) ? 42 : (ks==1) ? 46 : (ks==2) ? 55 : 64;

    unsigned tgt = NBLK;
    for (int d = 0; d < Tn; d++){
        unsigned short* Ac = (d & 1) ? A1 : A0;
        unsigned short* An = (d & 1) ? A0 : A1;
        const unsigned short* Af = Ac + (size_t)rg*KCD*512 + l*8;

        // ---------------- phase A ----------------
        floatx4 acc0={0,0,0,0}, acc1={0,0,0,0}, acc2={0,0,0,0}, acc3={0,0,0,0};
        #pragma unroll 2
        for (int kc = ka0; kc < ka1; kc++){
            short8 a  = ld_cg_s8(Af + kc*512);
            short8 b0 = *(const short8*)(Bf + (0*KCD + kc)*512);
            short8 b1 = *(const short8*)(Bf + (1*KCD + kc)*512);
            short8 b2 = *(const short8*)(Bf + (2*KCD + kc)*512);
            short8 b3 = *(const short8*)(Bf + (3*KCD + kc)*512);
            acc0 = __builtin_amdgcn_mfma_f32_16x16x32_bf16(a, b0, acc0, 0, 0, 0);
            acc1 = __builtin_amdgcn_mfma_f32_16x16x32_bf16(a, b1, acc1, 0, 0, 0);
            acc2 = __builtin_amdgcn_mfma_f32_16x16x32_bf16(a, b2, acc2, 0, 0, 0);
            acc3 = __builtin_amdgcn_mfma_f32_16x16x32_bf16(a, b3, acc3, 0, 0, 0);
        }
        if (ks == 1){   // attnq: waves 2,3 -> tile (rg, y)
            const unsigned short* Aq = Ac + ((size_t)rg*KCD + 32)*512 + l*8;
            const unsigned short* Bq = Watt + (size_t)y*KCQ*512 + l*8;
            floatx4 qa = {0,0,0,0};
            #pragma unroll 4
            for (int kc = 0; kc < KCQ; kc++){
                short8 a = ld_cg_s8(Aq + kc*512);
                short8 b = *(const short8*)(Bq + kc*512);
                qa = __builtin_amdgcn_mfma_f32_16x16x32_bf16(a, b, qa, 0, 0, 0);
            }
            #pragma unroll
            for (int r = 0; r < 4; r++)
                st_cg16(qbf + (size_t)(m0 + q4*4 + r)*Hn + y*16 + col, f2bf(qa[r]));
        }
        if (d > 0 && x == 0 && w >= 6){   // pred_{d-1} = fc(h_{d-1})
            const int b = y*2 + (w & 1);
            float p = fcdot(hplain, fcW, b, l);
            if (l == 0){
                float pv = p + fcb[0];
                out[b*Tn + (d-1)] = pv;
                st_cg16(Ac + (((size_t)(b >> 4))*KCD + 64)*512 + (b & 15)*8, f2bf(pv));
            }
        }
        gbar(bar, tgt); tgt += NBLK;

        // ---------------- phase B: attention ----------------
        if (blockIdx.x < Bn){
            const int b = blockIdx.x;
            float* ctxl = smem;
            float* mred = smem + 8192;
            float* lred = smem + 8200;
            float qv[16];
            {
                const unsigned short* qp = qbf + (size_t)b*Hn + l*16;
                uintx4 q0 = ld_cg_u4(qp), q1 = ld_cg_u4(qp + 8);
                unpack8v(q0, qv); unpack8v(q1, qv + 8);
            }
            float mx = -1e30f, lsum = 0.0f;
            float cacc[16];
            #pragma unroll
            for (int i = 0; i < 16; i++) cacc[i] = 0.0f;

            const uintx4* ebase = (const uintx4*)(enco + (size_t)b*Sn*Hn) + l*2;
            for (int s = w; s < Sn; s += 8){
                uintx4 e0 = ebase[(size_t)s*128];
                uintx4 e1 = ebase[(size_t)s*128 + 1];
                float ev[16];
                unpack8v(e0, ev); unpack8v(e1, ev + 8);
                float part = 0.0f;
                #pragma unroll
                for (int i = 0; i < 16; i++) part = fmaf(qv[i], ev[i], part);
                #pragma unroll
                for (int off = 32; off; off >>= 1) part += __shfl_down(part, off);
                float e = __shfl(part, 0);
                float mn = fmaxf(mx, e);
                float corr = expf(mx - mn);
                float p = expf(e - mn);
                lsum = lsum*corr + p;
                if (corr != 1.0f){
                    #pragma unroll
                    for (int i = 0; i < 16; i++) cacc[i] *= corr;
                }
                #pragma unroll
                for (int i = 0; i < 16; i++) cacc[i] = fmaf(p, ev[i], cacc[i]);
                mx = mn;
            }
            if (l == 0){ mred[w] = mx; lred[w] = lsum; }
            __syncthreads();
            float M = mred[0];
            #pragma unroll
            for (int k = 1; k < 8; k++) M = fmaxf(M, mred[k]);
            float corr2 = expf(mx - M);
            #pragma unroll
            for (int j = 0; j < 16; j++) ctxl[w*1024 + j*64 + l] = cacc[j]*corr2;
            __syncthreads();
            float L = 0.0f;
            #pragma unroll
            for (int k = 0; k < 8; k++) L += lred[k]*expf(mred[k] - M);
            float invL = 1.0f / L;

            const int u0 = 2*tid;
            float s0 = 0.0f, s1 = 0.0f;
            #pragma unroll
            for (int k = 0; k < 8; k++){
                s0 += ctxl[k*1024 + (u0 & 15)*64 + (u0 >> 4)];
                s1 += ctxl[k*1024 + ((u0+1) & 15)*64 + ((u0+1) >> 4)];
            }
            unsigned cvu = (unsigned)f2bf(s0*invL) | ((unsigned)f2bf(s1*invL) << 16);
            const int kcw = u0 >> 5;
            const int lanep2 = (b & 15) + ((u0 >> 3) & 3)*16;
            st_cg32(Ac + ((((size_t)(b >> 4))*KCD + kcw)*64 + lanep2)*8 + (u0 & 7), cvu);
        }
        gbar(bar, tgt); tgt += NBLK;

        // ---------------- phase C ----------------
        {
            const int kc0 = ks*8;
            #pragma unroll 2
            for (int kk = 0; kk < 8; kk++){
                const int kc = kc0 + kk;
                short8 a  = ld_cg_s8(Af + kc*512);
                short8 b0 = *(const short8*)(Bf + (0*KCD + kc)*512);
                short8 b1 = *(const short8*)(Bf + (1*KCD + kc)*512);
                short8 b2 = *(const short8*)(Bf + (2*KCD + kc)*512);
                short8 b3 = *(const short8*)(Bf + (3*KCD + kc)*512);
                acc0 = __builtin_amdgcn_mfma_f32_16x16x32_bf16(a, b0, acc0, 0, 0, 0);
                acc1 = __builtin_amdgcn_mfma_f32_16x16x32_bf16(a, b1, acc1, 0, 0, 0);
                acc2 = __builtin_amdgcn_mfma_f32_16x16x32_bf16(a, b2, acc2, 0, 0, 0);
                acc3 = __builtin_amdgcn_mfma_f32_16x16x32_bf16(a, b3, acc3, 0, 0, 0);
            }
            if (ks == 3){   // prev_y + pad chunk
                short8 a  = ld_cg_s8(Af + 64*512);
                short8 b0 = *(const short8*)(Bf + (0*KCD + 64)*512);
                short8 b1 = *(const short8*)(Bf + (1*KCD + 64)*512);
                short8 b2 = *(const short8*)(Bf + (2*KCD + 64)*512);
                short8 b3 = *(const short8*)(Bf + (3*KCD + 64)*512);
                acc0 = __builtin_amdgcn_mfma_f32_16x16x32_bf16(a, b0, acc0, 0, 0, 0);
                acc1 = __builtin_amdgcn_mfma_f32_16x16x32_bf16(a, b1, acc1, 0, 0, 0);
                acc2 = __builtin_amdgcn_mfma_f32_16x16x32_bf16(a, b2, acc2, 0, 0, 0);
                acc3 = __builtin_amdgcn_mfma_f32_16x16x32_bf16(a, b3, acc3, 0, 0, 0);
            }
        }
        if (ks != 0){
            float* rp = smem + ((ks-1)*2 + rgw)*1024;
            #pragma unroll
            for (int r = 0; r < 4; r++){
                rp[( 0 + r)*64 + l] = acc0[r];
                rp[( 4 + r)*64 + l] = acc1[r];
                rp[( 8 + r)*64 + l] = acc2[r];
                rp[(12 + r)*64 + l] = acc3[r];
            }
        }
        __syncthreads();
        if (ks == 0){
            const float* r0 = smem + rgw*1024;
            const float* r1 = smem + (2 + rgw)*1024;
            const float* r2 = smem + (4 + rgw)*1024;
            #pragma unroll
            for (int r = 0; r < 4; r++){
                acc0[r] += r0[( 0+r)*64 + l] + r1[( 0+r)*64 + l] + r2[( 0+r)*64 + l];
                acc1[r] += r0[( 4+r)*64 + l] + r1[( 4+r)*64 + l] + r2[( 4+r)*64 + l];
                acc2[r] += r0[( 8+r)*64 + l] + r1[( 8+r)*64 + l] + r2[( 8+r)*64 + l];
                acc3[r] += r0[(12+r)*64 + l] + r1[(12+r)*64 + l] + r2[(12+r)*64 + l];
            }
            #pragma unroll
            for (int r = 0; r < 4; r++){
                const int m = m0 + q4*4 + r;
                float gi = acc0[r] + bi;
                float gf = acc1[r] + bf_;
                float gg = acc2[r] + bg;
                float go = acc3[r] + bo;
                float co = cbuf[(size_t)m*Hn + u];
                float cn = sigmoidf_(gf)*co + sigmoidf_(gi)*tanhf(gg);
                float hv = sigmoidf_(go)*tanhf(cn);
                cbuf[(size_t)m*Hn + u] = cn;
                unsigned short hb = f2bf(hv);
                const int lanep = (q4*4 + r) + lsh;
                st_cg16(An + (((size_t)rg*KCD + 32 + (u >> 5))*64 + lanep)*8 + (u & 7), hb);
                st_cg16(hplain + (size_t)m*Hn + u, hb);
            }
        }
        gbar(bar, tgt); tgt += NBLK;
    }

    // final pred: out[:, Tn-1] = fc(h_{Tn-1})
    if (x == 0 && w >= 6){
        const int b = y*2 + (w & 1);
        float p = fcdot(hplain, fcW, b, l);
        if (l == 0) out[b*Tn + (Tn - 1)] = p + fcb[0];
    }
}

extern "C" void kernel_launch(void* const* d_in, const int* in_sizes, int n_in,
                              void* d_out, int out_size, void* d_ws, size_t ws_size,
                              hipStream_t stream){
    const float* src  = (const float*)d_in[0];
    const float* eWih = (const float*)d_in[1];
    const float* eWhh = (const float*)d_in[2];
    const float* ebih = (const float*)d_in[3];
    const float* ebhh = (const float*)d_in[4];
    const float* dWih = (const float*)d_in[5];
    const float* dWhh = (const float*)d_in[6];
    const float* dbih = (const float*)d_in[7];
    const float* dbhh = (const float*)d_in[8];
    const float* attnW= (const float*)d_in[9];
    const float* fcW  = (const float*)d_in[10];
    const float* fcb  = (const float*)d_in[11];
    float* out = (float*)d_out;

    char* base = (char*)d_ws;
    auto alloc = [&](size_t bytes){ void* p = base; base += (bytes + 255) & ~255ull; return p; };
    unsigned short* Wencf = (unsigned short*)alloc((size_t)256*KCE*512*2);
    float*          benc  = (float*)alloc(G4*4);
    unsigned short* Wdecf = (unsigned short*)alloc((size_t)256*KCD*512*2);
    float*          bdec  = (float*)alloc(G4*4);
    unsigned short* Wattf = (unsigned short*)alloc((size_t)64*KCQ*512*2);
    unsigned short* srcf  = (unsigned short*)alloc((size_t)Sn*8*2*512*2);
    unsigned short* enco  = (unsigned short*)alloc((size_t)Bn*Sn*Hn*2);
    unsigned short* hf0   = (unsigned short*)alloc((size_t)8*32*512*2);
    unsigned short* hf1   = (unsigned short*)alloc((size_t)8*32*512*2);
    float*          cbuf  = (float*)alloc((size_t)Bn*Hn*4);
    unsigned short* A0f   = (unsigned short*)alloc((size_t)8*KCD*512*2);
    unsigned short* A1f   = (unsigned short*)alloc((size_t)8*KCD*512*2);
    unsigned short* qbf   = (unsigned short*)alloc((size_t)Bn*Hn*2);
    unsigned short* hplain= (unsigned short*)alloc((size_t)Bn*Hn*2);
    unsigned*       bars  = (unsigned*)alloc(4*4);

    conv_srcf<<<2048, 256, 0, stream>>>(src, srcf);
    pack_encf<<<4096, 256, 0, stream>>>(eWih, eWhh, ebih, ebhh, Wencf, benc);
    pack_decf<<<8192, 256, 0, stream>>>(dWih, dWhh, dbih, dbhh, Wdecf, bdec);
    pack_attnf<<<1024, 256, 0, stream>>>(attnW, Wattf);
    init_ws<<<1040, 256, 0, stream>>>(hf0, cbuf, A0f, A1f, bars);

    enc_loop<<<NBLK, 256, 0, stream>>>(srcf, Wencf, benc, cbuf, hf0, hf1,
                                       enco, A0f, bars + 0);
    dec_loop<<<NBLK, 512, 0, stream>>>(A0f, A1f, Wdecf, bdec, cbuf, Wattf,
                                       qbf, enco, hplain, fcW, fcb, out, bars + 1);
}

// Round 3
// 9690.810 us; speedup vs baseline: 2.8732x; 1.0494x over previous
//
#include <hip/hip_runtime.h>
#include <math.h>

#define Bn   128
#define Sn   336
#define INd  64
#define Hn   1024
#define Tn   96
#define G4   4096
#define KCE  34     // enc k-chunks: [x(64) | h(1024)]
#define KCD  65     // dec k-chunks: [ctx(1024) | h(1024) | prev_y | pad]
#define KCQ  32     // attn query k-chunks
#define NBLK 256
#define SHALF 168   // S split per attention partial block

typedef __attribute__((ext_vector_type(8))) short short8;
typedef __attribute__((ext_vector_type(4))) float floatx4;
typedef __attribute__((ext_vector_type(4))) unsigned int uintx4;
typedef unsigned long long u64t;

__device__ __forceinline__ float sigmoidf_(float x){ return 1.0f/(1.0f+expf(-x)); }

__device__ __forceinline__ unsigned short f2bf(float f){
    union { float f; unsigned u; } v; v.f = f;
    unsigned r = v.u + 0x7fffu + ((v.u >> 16) & 1u);
    return (unsigned short)(r >> 16);
}
__device__ __forceinline__ float bflo(unsigned u){ union{unsigned u; float f;} v; v.u = u << 16;        return v.f; }
__device__ __forceinline__ float bfhi(unsigned u){ union{unsigned u; float f;} v; v.u = u & 0xffff0000u; return v.f; }
__device__ __forceinline__ void unpack8v(uintx4 v, float* f){
    f[0]=bflo(v.x); f[1]=bfhi(v.x); f[2]=bflo(v.y); f[3]=bfhi(v.y);
    f[4]=bflo(v.z); f[5]=bfhi(v.z); f[6]=bflo(v.w); f[7]=bfhi(v.w);
}

// ---- LLC-coherent (agent-scope, L2-bypassing) access helpers -------------
union Frag16 { u64t q[2]; short8 s8; uintx4 u4; };
union F2 { u64t q; float f[2]; };

__device__ __forceinline__ short8 ld_cg_s8(const unsigned short* p){
    Frag16 r;
    r.q[0] = __hip_atomic_load((const u64t*)p,     __ATOMIC_RELAXED, __HIP_MEMORY_SCOPE_AGENT);
    r.q[1] = __hip_atomic_load((const u64t*)p + 1, __ATOMIC_RELAXED, __HIP_MEMORY_SCOPE_AGENT);
    return r.s8;
}
__device__ __forceinline__ uintx4 ld_cg_u4(const unsigned short* p){
    Frag16 r;
    r.q[0] = __hip_atomic_load((const u64t*)p,     __ATOMIC_RELAXED, __HIP_MEMORY_SCOPE_AGENT);
    r.q[1] = __hip_atomic_load((const u64t*)p + 1, __ATOMIC_RELAXED, __HIP_MEMORY_SCOPE_AGENT);
    return r.u4;
}
__device__ __forceinline__ void st_cg16(unsigned short* p, unsigned short v){
    asm volatile("global_store_short %0, %1, off sc0 sc1" :: "v"(p), "v"((unsigned)v) : "memory");
}
__device__ __forceinline__ void st_cg32(unsigned short* p, unsigned v){
    asm volatile("global_store_dword %0, %1, off sc0 sc1" :: "v"(p), "v"(v) : "memory");
}
__device__ __forceinline__ void st_cg64(float* p, float a, float b){
    F2 v; v.f[0] = a; v.f[1] = b;
    __hip_atomic_store((u64t*)p, v.q, __ATOMIC_RELAXED, __HIP_MEMORY_SCOPE_AGENT);
}
__device__ __forceinline__ F2 ld_cg64(const float* p){
    F2 v; v.q = __hip_atomic_load((const u64t*)p, __ATOMIC_RELAXED, __HIP_MEMORY_SCOPE_AGENT);
    return v;
}

// Two-level flush-free grid barrier. Single-line 256-way fetch_add serialized
// (~4-6us); split arrival into 8 group lines (32 adds each, parallel across
// lines) + 8-way global + per-group release word. Monotonic counters.
// Layout (u32): loc[g]=g*32, glob=256, rel[g]=512+g*32  (128B line spacing).
__device__ __forceinline__ void gbar2(unsigned* bb, int g, bool rep, unsigned step){
    asm volatile("s_waitcnt vmcnt(0)" ::: "memory");
    __syncthreads();
    if (threadIdx.x == 0){
        __hip_atomic_fetch_add(bb + g*32, 1u, __ATOMIC_RELAXED, __HIP_MEMORY_SCOPE_AGENT);
        if (rep){
            while (__hip_atomic_load(bb + g*32, __ATOMIC_RELAXED, __HIP_MEMORY_SCOPE_AGENT) < step*32u)
                __builtin_amdgcn_s_sleep(1);
            __hip_atomic_fetch_add(bb + 256, 1u, __ATOMIC_RELAXED, __HIP_MEMORY_SCOPE_AGENT);
            while (__hip_atomic_load(bb + 256, __ATOMIC_RELAXED, __HIP_MEMORY_SCOPE_AGENT) < step*8u)
                __builtin_amdgcn_s_sleep(1);
            __hip_atomic_store(bb + 512 + g*32, step, __ATOMIC_RELAXED, __HIP_MEMORY_SCOPE_AGENT);
        } else {
            while (__hip_atomic_load(bb + 512 + g*32, __ATOMIC_RELAXED, __HIP_MEMORY_SCOPE_AGENT) < step)
                __builtin_amdgcn_s_sleep(1);
        }
    }
    __syncthreads();
}

// ===================== fragment-order packing ==============================
__global__ void pack_encf(const float* __restrict__ Wih, const float* __restrict__ Whh,
                          const float* __restrict__ bih, const float* __restrict__ bhh,
                          unsigned short* __restrict__ Wp, float* __restrict__ bc){
    long n = (long)256*KCE*512;
    for (long idx = (long)blockIdx.x*256 + threadIdx.x; idx < n; idx += (long)gridDim.x*256){
        int j = (int)(idx & 7), l = (int)((idx >> 3) & 63);
        int kc = (int)((idx >> 9) % KCE);
        int s  = (int)(idx / (KCE*512));
        int c = l & 15, kg = l >> 4;
        int k = kc*32 + kg*8 + j;
        int gate = s & 3, unit = (s >> 2)*16 + c;
        int orig = gate*Hn + unit;
        float v = (k < INd) ? Wih[orig*INd + k] : Whh[(size_t)orig*Hn + (k - INd)];
        Wp[idx] = f2bf(v);
    }
    int tid = blockIdx.x*256 + threadIdx.x;
    if (tid < G4){
        int g = (tid >> 4) & 3, u = (tid >> 6)*16 + (tid & 15);
        int orig = g*Hn + u;
        bc[tid] = bih[orig] + bhh[orig];
    }
}

__global__ void pack_decf(const float* __restrict__ Wih, const float* __restrict__ Whh,
                          const float* __restrict__ bih, const float* __restrict__ bhh,
                          unsigned short* __restrict__ Wp, float* __restrict__ bc){
    long n = (long)256*KCD*512;
    for (long idx = (long)blockIdx.x*256 + threadIdx.x; idx < n; idx += (long)gridDim.x*256){
        int j = (int)(idx & 7), l = (int)((idx >> 3) & 63);
        int kc = (int)((idx >> 9) % KCD);
        int s  = (int)(idx / (KCD*512));
        int c = l & 15, kg = l >> 4;
        int k = kc*32 + kg*8 + j;
        int gate = s & 3, unit = (s >> 2)*16 + c;
        int orig = gate*Hn + unit;
        float v;
        if (k < Hn)          v = Wih[(size_t)orig*(Hn+1) + 1 + k];     // ctx
        else if (k < 2*Hn)   v = Whh[(size_t)orig*Hn + (k - Hn)];      // h
        else if (k == 2*Hn)  v = Wih[(size_t)orig*(Hn+1)];             // prev_y
        else                 v = 0.0f;                                  // pad
        Wp[idx] = f2bf(v);
    }
    int tid = blockIdx.x*256 + threadIdx.x;
    if (tid < G4){
        int g = (tid >> 4) & 3, u = (tid >> 6)*16 + (tid & 15);
        int orig = g*Hn + u;
        bc[tid] = bih[orig] + bhh[orig];
    }
}

__global__ void pack_attnf(const float* __restrict__ w, unsigned short* __restrict__ Wp){
    int n = 64*KCQ*512;
    for (int idx = blockIdx.x*256 + threadIdx.x; idx < n; idx += gridDim.x*256){
        int j = idx & 7, l = (idx >> 3) & 63;
        int kc = (idx >> 9) & 31;
        int s  = idx >> 14;
        int nn = s*16 + (l & 15);
        int k = kc*32 + (l >> 4)*8 + j;
        Wp[idx] = f2bf(w[(size_t)nn*Hn + k]);
    }
}

// src A-fragments: [t][rg(8)][kc(2)][lane][8]; row b = rg*16 + (l&15)
__global__ void conv_srcf(const float* __restrict__ s, unsigned short* __restrict__ d){
    int n = Sn*8*2*512;
    for (int idx = blockIdx.x*256 + threadIdx.x; idx < n; idx += gridDim.x*256){
        int j = idx & 7, l = (idx >> 3) & 63;
        int kc = (idx >> 9) & 1, rg = (idx >> 10) & 7, t = idx >> 13;
        int b = rg*16 + (l & 15);
        int k = kc*32 + (l >> 4)*8 + j;
        d[idx] = f2bf(s[((size_t)b*Sn + t)*INd + k]);
    }
}

__global__ void init_ws(unsigned short* __restrict__ hf0, float* __restrict__ cbuf,
                        unsigned short* __restrict__ A0, unsigned short* __restrict__ A1,
                        unsigned* __restrict__ bars){
    int t0 = blockIdx.x*256 + threadIdx.x;
    if (t0 < 2048) bars[t0] = 0;
    for (int i = t0; i < 8*KCD*512; i += gridDim.x*256){
        A0[i] = 0; A1[i] = 0;
        if (i < 8*32*512) hf0[i] = 0;
        if (i < Bn*Hn) cbuf[i] = 0.0f;
    }
}

// XCD-aware swizzle: blocks on XCD k own y in [k*8, k*8+8) -> per-XCD weight
// slice (enc ~1.1MB, dec ~2.1MB) stays L2-resident across all steps.
__device__ __forceinline__ void swz(int b, int& x, int& y){
    int xcd = b & 7, li = b >> 3;
    y = xcd*8 + (li & 7);
    x = li >> 3;
}

// fc dot: pred[b] = h[b,:] . fcW  (lane0 of the wave holds the result)
__device__ __forceinline__ float fcdot(const unsigned short* __restrict__ hplain,
                                       const float* __restrict__ fcW, int b, int l){
    const unsigned short* hp = hplain + (size_t)b*Hn + l*16;
    uintx4 h0 = ld_cg_u4(hp), h1 = ld_cg_u4(hp + 8);
    float hf[16]; unpack8v(h0, hf); unpack8v(h1, hf + 8);
    float p = 0.0f;
    #pragma unroll
    for (int i = 0; i < 16; i++) p = fmaf(hf[i], fcW[l*16 + i], p);
    #pragma unroll
    for (int off = 32; off; off >>= 1) p += __shfl_down(p, off);
    return p;
}

// ===================== persistent encoder: 336 steps, 1 barrier each =======
__global__ __launch_bounds__(256, 1)
void enc_loop(const unsigned short* __restrict__ srcfrag,  // [336][8][2][512]
              const unsigned short* __restrict__ Wf,       // [256][KCE][512]
              const float* __restrict__ bc, float* __restrict__ cbuf,
              unsigned short* __restrict__ hf0,            // [8][32][512]
              unsigned short* __restrict__ hf1,
              unsigned short* __restrict__ enco,
              unsigned short* __restrict__ adec0,          // [8][KCD][512]
              unsigned* __restrict__ bar)
{
    __shared__ float red[2][16][65];
    const int tid = threadIdx.x, l = tid & 63, w = tid >> 6;
    const int rgw = w & 1, kh = w >> 1;
    int x, y; swz(blockIdx.x, x, y);
    const int g = blockIdx.x & 7;
    const bool rep = (blockIdx.x >> 3) == 0;
    const int rg = x*2 + rgw;
    const int m0 = rg*16;
    const unsigned short* Bf = Wf + (size_t)(4*y)*KCE*512 + l*8;

    const int col = l & 15, q = l >> 4;
    const int u = y*16 + col;
    const float bi  = bc[y*64 + col];
    const float bf_ = bc[y*64 + 16 + col];
    const float bg  = bc[y*64 + 32 + col];
    const float bo  = bc[y*64 + 48 + col];
    const int lsh = ((u >> 3) & 3) * 16;

    unsigned bstep = 0;
    for (int t = 0; t < Sn; t++){
        const unsigned short* hin = (t & 1) ? hf1 : hf0;
        unsigned short* hout      = (t & 1) ? hf0 : hf1;
        const unsigned short* Ah = hin + (size_t)rg*32*512 + l*8;
        floatx4 acc0={0,0,0,0}, acc1={0,0,0,0}, acc2={0,0,0,0}, acc3={0,0,0,0};

        if (kh == 0){
            // prefetch all LLC h-fragments off the MFMA critical path
            short8 ah[15];
            #pragma unroll
            for (int hc = 0; hc < 15; hc++) ah[hc] = ld_cg_s8(Ah + hc*512);
            const unsigned short* Ax = srcfrag + ((size_t)t*8 + rg)*2*512 + l*8;
            #pragma unroll
            for (int kc = 0; kc < 2; kc++){
                short8 a  = *(const short8*)(Ax + kc*512);
                short8 b0 = *(const short8*)(Bf + (0*KCE + kc)*512);
                short8 b1 = *(const short8*)(Bf + (1*KCE + kc)*512);
                short8 b2 = *(const short8*)(Bf + (2*KCE + kc)*512);
                short8 b3 = *(const short8*)(Bf + (3*KCE + kc)*512);
                acc0 = __builtin_amdgcn_mfma_f32_16x16x32_bf16(a, b0, acc0, 0, 0, 0);
                acc1 = __builtin_amdgcn_mfma_f32_16x16x32_bf16(a, b1, acc1, 0, 0, 0);
                acc2 = __builtin_amdgcn_mfma_f32_16x16x32_bf16(a, b2, acc2, 0, 0, 0);
                acc3 = __builtin_amdgcn_mfma_f32_16x16x32_bf16(a, b3, acc3, 0, 0, 0);
            }
            #pragma unroll
            for (int hc = 0; hc < 15; hc++){
                short8 b0 = *(const short8*)(Bf + (0*KCE + hc + 2)*512);
                short8 b1 = *(const short8*)(Bf + (1*KCE + hc + 2)*512);
                short8 b2 = *(const short8*)(Bf + (2*KCE + hc + 2)*512);
                short8 b3 = *(const short8*)(Bf + (3*KCE + hc + 2)*512);
                acc0 = __builtin_amdgcn_mfma_f32_16x16x32_bf16(ah[hc], b0, acc0, 0, 0, 0);
                acc1 = __builtin_amdgcn_mfma_f32_16x16x32_bf16(ah[hc], b1, acc1, 0, 0, 0);
                acc2 = __builtin_amdgcn_mfma_f32_16x16x32_bf16(ah[hc], b2, acc2, 0, 0, 0);
                acc3 = __builtin_amdgcn_mfma_f32_16x16x32_bf16(ah[hc], b3, acc3, 0, 0, 0);
            }
        } else {
            short8 ah[17];
            #pragma unroll
            for (int i = 0; i < 17; i++) ah[i] = ld_cg_s8(Ah + (15 + i)*512);
            #pragma unroll
            for (int i = 0; i < 17; i++){
                short8 b0 = *(const short8*)(Bf + (0*KCE + i + 17)*512);
                short8 b1 = *(const short8*)(Bf + (1*KCE + i + 17)*512);
                short8 b2 = *(const short8*)(Bf + (2*KCE + i + 17)*512);
                short8 b3 = *(const short8*)(Bf + (3*KCE + i + 17)*512);
                acc0 = __builtin_amdgcn_mfma_f32_16x16x32_bf16(ah[i], b0, acc0, 0, 0, 0);
                acc1 = __builtin_amdgcn_mfma_f32_16x16x32_bf16(ah[i], b1, acc1, 0, 0, 0);
                acc2 = __builtin_amdgcn_mfma_f32_16x16x32_bf16(ah[i], b2, acc2, 0, 0, 0);
                acc3 = __builtin_amdgcn_mfma_f32_16x16x32_bf16(ah[i], b3, acc3, 0, 0, 0);
            }
            #pragma unroll
            for (int r = 0; r < 4; r++){
                red[rgw][ 0 + r][l] = acc0[r];
                red[rgw][ 4 + r][l] = acc1[r];
                red[rgw][ 8 + r][l] = acc2[r];
                red[rgw][12 + r][l] = acc3[r];
            }
        }
        __syncthreads();
        if (kh == 0){
            #pragma unroll
            for (int r = 0; r < 4; r++){
                acc0[r] += red[rgw][ 0 + r][l];
                acc1[r] += red[rgw][ 4 + r][l];
                acc2[r] += red[rgw][ 8 + r][l];
                acc3[r] += red[rgw][12 + r][l];
            }
            #pragma unroll
            for (int r = 0; r < 4; r++){
                const int m = m0 + q*4 + r;
                float gi = acc0[r] + bi;
                float gf = acc1[r] + bf_;
                float gg = acc2[r] + bg;
                float go = acc3[r] + bo;
                float co = cbuf[(size_t)m*Hn + u];
                float cn = sigmoidf_(gf)*co + sigmoidf_(gi)*tanhf(gg);
                float hv = sigmoidf_(go)*tanhf(cn);
                cbuf[(size_t)m*Hn + u] = cn;
                unsigned short hb = f2bf(hv);
                const int lanep = (q*4 + r) + lsh;
                st_cg16(hout + (((size_t)rg*32 + (u >> 5))*64 + lanep)*8 + (u & 7), hb);
                enco[((size_t)m*Sn + t)*Hn + u] = hb;   // cached; flushed at kernel end
                if (t == Sn-1) adec0[(((size_t)rg*KCD + 32 + (u >> 5))*64 + lanep)*8 + (u & 7)] = hb;
            }
        }
        bstep++; gbar2(bar, g, rep, bstep);
    }
}

// ===================== persistent decoder: 96 steps, 4 barriers each =======
// 256 blocks x 512 thr (8 waves: rgw=w&1, ks=w>>1).
// Phase A: dec-GEMM h-part (8 chunks per ks) + attnq split-K over ks (reuses
//          the SAME prefetched h-fragments; LDS reduce, ks==0 writes q) +
//          pred=fc(h_{d-1}) (x==0, w>=6).
// Phase B: attention partials — 2 blocks per batch (S halves of 168), online
//          softmax, writes f32 partial ctx + (m,l) via LLC.
// Phase B2: combine partials (blocks 0..127) -> bf16 ctx fragments.
// Phase C: ctx GEMM (kc0..31) + prev_y (kc64, ks==3) + LDS split-K reduce +
//          LSTM epilogue -> h fragments + plain h.
__global__ __launch_bounds__(512, 1)
void dec_loop(unsigned short* __restrict__ A0, unsigned short* __restrict__ A1,
              const unsigned short* __restrict__ Wdec,    // [256][KCD][512]
              const float* __restrict__ bdec, float* __restrict__ cbuf,
              const unsigned short* __restrict__ Watt,    // [64][KCQ][512]
              unsigned short* __restrict__ qbf,           // [128][1024] bf16
              const unsigned short* __restrict__ enco,    // [128][336][1024]
              unsigned short* __restrict__ hplain,        // [128][1024] bf16
              float* __restrict__ pctx,                   // [2][128][1024] f32
              float* __restrict__ pml,                    // [2][128][2] f32
              const float* __restrict__ fcW, const float* __restrict__ fcb,
              float* __restrict__ out, unsigned* __restrict__ bar)
{
    __shared__ float smem[8224];   // A: qred[8][4][64]; B: ctxl+mred+lred; C: redc
    const int tid = threadIdx.x, l = tid & 63, w = tid >> 6;
    const int rgw = w & 1, ks = w >> 1;
    int x, y; swz(blockIdx.x, x, y);
    const int g = blockIdx.x & 7;
    const bool rep = (blockIdx.x >> 3) == 0;
    const int rg = x*2 + rgw, m0 = rg*16;
    const unsigned short* Bf = Wdec + (size_t)(4*y)*KCD*512 + l*8;
    const unsigned short* Bq = Watt + (size_t)y*KCQ*512 + l*8;

    const int col = l & 15, q4 = l >> 4;
    const int u = y*16 + col;
    const float bi  = bdec[y*64 + col];
    const float bf_ = bdec[y*64 + 16 + col];
    const float bg  = bdec[y*64 + 32 + col];
    const float bo  = bdec[y*64 + 48 + col];
    const int lsh = ((u >> 3) & 3) * 16;
    // attention partial assignment: 2 blocks per batch
    const int ab   = blockIdx.x & 127;        // batch
    const int part = blockIdx.x >> 7;         // S half

    unsigned bstep = 0;
    for (int d = 0; d < Tn; d++){
        unsigned short* Ac = (d & 1) ? A1 : A0;
        unsigned short* An = (d & 1) ? A0 : A1;
        const unsigned short* Af = Ac + (size_t)rg*KCD*512 + l*8;

        // ---------------- phase A ----------------
        floatx4 acc0={0,0,0,0}, acc1={0,0,0,0}, acc2={0,0,0,0}, acc3={0,0,0,0};
        {
            short8 aA[8];
            #pragma unroll
            for (int kk = 0; kk < 8; kk++)
                aA[kk] = ld_cg_s8(Af + (32 + ks*8 + kk)*512);
            floatx4 qa = {0,0,0,0};
            #pragma unroll
            for (int kk = 0; kk < 8; kk++){
                const int kc = 32 + ks*8 + kk;
                short8 b0 = *(const short8*)(Bf + (0*KCD + kc)*512);
                short8 b1 = *(const short8*)(Bf + (1*KCD + kc)*512);
                short8 b2 = *(const short8*)(Bf + (2*KCD + kc)*512);
                short8 b3 = *(const short8*)(Bf + (3*KCD + kc)*512);
                short8 bq = *(const short8*)(Bq + (ks*8 + kk)*512);
                acc0 = __builtin_amdgcn_mfma_f32_16x16x32_bf16(aA[kk], b0, acc0, 0, 0, 0);
                acc1 = __builtin_amdgcn_mfma_f32_16x16x32_bf16(aA[kk], b1, acc1, 0, 0, 0);
                acc2 = __builtin_amdgcn_mfma_f32_16x16x32_bf16(aA[kk], b2, acc2, 0, 0, 0);
                acc3 = __builtin_amdgcn_mfma_f32_16x16x32_bf16(aA[kk], b3, acc3, 0, 0, 0);
                qa   = __builtin_amdgcn_mfma_f32_16x16x32_bf16(aA[kk], bq, qa, 0, 0, 0);
            }
            #pragma unroll
            for (int r = 0; r < 4; r++) smem[(w*4 + r)*64 + l] = qa[r];
        }
        __syncthreads();
        if (ks == 0){   // sum attnq split-K partials, write q
            #pragma unroll
            for (int r = 0; r < 4; r++){
                float s = smem[((0*2+rgw)*4 + r)*64 + l] + smem[((1*2+rgw)*4 + r)*64 + l]
                        + smem[((2*2+rgw)*4 + r)*64 + l] + smem[((3*2+rgw)*4 + r)*64 + l];
                st_cg16(qbf + (size_t)(m0 + q4*4 + r)*Hn + y*16 + col, f2bf(s));
            }
        }
        if (d > 0 && x == 0 && w >= 6){   // pred_{d-1} = fc(h_{d-1})
            const int b = y*2 + (w & 1);
            float p = fcdot(hplain, fcW, b, l);
            if (l == 0){
                float pv = p + fcb[0];
                out[b*Tn + (d-1)] = pv;
                st_cg16(Ac + (((size_t)(b >> 4))*KCD + 64)*512 + (b & 15)*8, f2bf(pv));
            }
        }
        bstep++; gbar2(bar, g, rep, bstep);

        // ---------------- phase B: attention partials (all 256 blocks) -----
        {
            float* ctxl = smem;
            float* mred = smem + 8192;
            float* lred = smem + 8200;
            float qv[16];
            {
                const unsigned short* qp = qbf + (size_t)ab*Hn + l*16;
                uintx4 q0 = ld_cg_u4(qp), q1 = ld_cg_u4(qp + 8);
                unpack8v(q0, qv); unpack8v(q1, qv + 8);
            }
            float mx = -1e30f, lsum = 0.0f;
            float cacc[16];
            #pragma unroll
            for (int i = 0; i < 16; i++) cacc[i] = 0.0f;

            const uintx4* ebase = (const uintx4*)(enco + (size_t)ab*Sn*Hn) + l*2;
            const int s0i = part*SHALF;
            for (int s = s0i + w; s < s0i + SHALF; s += 8){
                uintx4 e0 = ebase[(size_t)s*128];
                uintx4 e1 = ebase[(size_t)s*128 + 1];
                float ev[16];
                unpack8v(e0, ev); unpack8v(e1, ev + 8);
                float pt = 0.0f;
                #pragma unroll
                for (int i = 0; i < 16; i++) pt = fmaf(qv[i], ev[i], pt);
                #pragma unroll
                for (int off = 32; off; off >>= 1) pt += __shfl_down(pt, off);
                float e = __shfl(pt, 0);
                float mn = fmaxf(mx, e);
                float corr = expf(mx - mn);
                float p = expf(e - mn);
                lsum = lsum*corr + p;
                if (corr != 1.0f){
                    #pragma unroll
                    for (int i = 0; i < 16; i++) cacc[i] *= corr;
                }
                #pragma unroll
                for (int i = 0; i < 16; i++) cacc[i] = fmaf(p, ev[i], cacc[i]);
                mx = mn;
            }
            if (l == 0){ mred[w] = mx; lred[w] = lsum; }
            __syncthreads();
            float M = mred[0];
            #pragma unroll
            for (int k = 1; k < 8; k++) M = fmaxf(M, mred[k]);
            float corr2 = expf(mx - M);
            #pragma unroll
            for (int j = 0; j < 16; j++) ctxl[w*1024 + j*64 + l] = cacc[j]*corr2;
            __syncthreads();
            float L = 0.0f;
            #pragma unroll
            for (int k = 0; k < 8; k++) L += lred[k]*expf(mred[k] - M);

            const int u0 = 2*tid;
            float s0 = 0.0f, s1 = 0.0f;
            #pragma unroll
            for (int k = 0; k < 8; k++){
                s0 += ctxl[k*1024 + (u0 & 15)*64 + (u0 >> 4)];
                s1 += ctxl[k*1024 + ((u0+1) & 15)*64 + ((u0+1) >> 4)];
            }
            st_cg64(pctx + ((size_t)part*128 + ab)*1024 + u0, s0, s1);
            if (tid == 0) st_cg64(pml + ((size_t)part*128 + ab)*2, M, L);
        }
        bstep++; gbar2(bar, g, rep, bstep);

        // ---------------- phase B2: combine partials (blocks 0..127) -------
        if (blockIdx.x < Bn){
            const int b = blockIdx.x;
            F2 ml0 = ld_cg64(pml + (size_t)b*2);
            F2 ml1 = ld_cg64(pml + (size_t)(128 + b)*2);
            float M = fmaxf(ml0.f[0], ml1.f[0]);
            float w0 = expf(ml0.f[0] - M), w1 = expf(ml1.f[0] - M);
            float invL = 1.0f / (ml0.f[1]*w0 + ml1.f[1]*w1);
            const int u0 = 2*tid;
            F2 c0 = ld_cg64(pctx + (size_t)b*1024 + u0);
            F2 c1 = ld_cg64(pctx + ((size_t)128 + b)*1024 + u0);
            float v0 = (c0.f[0]*w0 + c1.f[0]*w1)*invL;
            float v1 = (c0.f[1]*w0 + c1.f[1]*w1)*invL;
            unsigned cvu = (unsigned)f2bf(v0) | ((unsigned)f2bf(v1) << 16);
            const int kcw = u0 >> 5;
            const int lanep2 = (b & 15) + ((u0 >> 3) & 3)*16;
            st_cg32(Ac + ((((size_t)(b >> 4))*KCD + kcw)*64 + lanep2)*8 + (u0 & 7), cvu);
        }
        bstep++; gbar2(bar, g, rep, bstep);

        // ---------------- phase C ----------------
        {
            short8 aC[8];
            #pragma unroll
            for (int kk = 0; kk < 8; kk++)
                aC[kk] = ld_cg_s8(Af + (ks*8 + kk)*512);
            #pragma unroll
            for (int kk = 0; kk < 8; kk++){
                const int kc = ks*8 + kk;
                short8 b0 = *(const short8*)(Bf + (0*KCD + kc)*512);
                short8 b1 = *(const short8*)(Bf + (1*KCD + kc)*512);
                short8 b2 = *(const short8*)(Bf + (2*KCD + kc)*512);
                short8 b3 = *(const short8*)(Bf + (3*KCD + kc)*512);
                acc0 = __builtin_amdgcn_mfma_f32_16x16x32_bf16(aC[kk], b0, acc0, 0, 0, 0);
                acc1 = __builtin_amdgcn_mfma_f32_16x16x32_bf16(aC[kk], b1, acc1, 0, 0, 0);
                acc2 = __builtin_amdgcn_mfma_f32_16x16x32_bf16(aC[kk], b2, acc2, 0, 0, 0);
                acc3 = __builtin_amdgcn_mfma_f32_16x16x32_bf16(aC[kk], b3, acc3, 0, 0, 0);
            }
            if (ks == 3){   // prev_y + pad chunk
                short8 a  = ld_cg_s8(Af + 64*512);
                short8 b0 = *(const short8*)(Bf + (0*KCD + 64)*512);
                short8 b1 = *(const short8*)(Bf + (1*KCD + 64)*512);
                short8 b2 = *(const short8*)(Bf + (2*KCD + 64)*512);
                short8 b3 = *(const short8*)(Bf + (3*KCD + 64)*512);
                acc0 = __builtin_amdgcn_mfma_f32_16x16x32_bf16(a, b0, acc0, 0, 0, 0);
                acc1 = __builtin_amdgcn_mfma_f32_16x16x32_bf16(a, b1, acc1, 0, 0, 0);
                acc2 = __builtin_amdgcn_mfma_f32_16x16x32_bf16(a, b2, acc2, 0, 0, 0);
                acc3 = __builtin_amdgcn_mfma_f32_16x16x32_bf16(a, b3, acc3, 0, 0, 0);
            }
        }
        if (ks != 0){
            float* rp = smem + ((ks-1)*2 + rgw)*1024;
            #pragma unroll
            for (int r = 0; r < 4; r++){
                rp[( 0 + r)*64 + l] = acc0[r];
                rp[( 4 + r)*64 + l] = acc1[r];
                rp[( 8 + r)*64 + l] = acc2[r];
                rp[(12 + r)*64 + l] = acc3[r];
            }
        }
        __syncthreads();
        if (ks == 0){
            const float* r0 = smem + rgw*1024;
            const float* r1 = smem + (2 + rgw)*1024;
            const float* r2 = smem + (4 + rgw)*1024;
            #pragma unroll
            for (int r = 0; r < 4; r++){
                acc0[r] += r0[( 0+r)*64 + l] + r1[( 0+r)*64 + l] + r2[( 0+r)*64 + l];
                acc1[r] += r0[( 4+r)*64 + l] + r1[( 4+r)*64 + l] + r2[( 4+r)*64 + l];
                acc2[r] += r0[( 8+r)*64 + l] + r1[( 8+r)*64 + l] + r2[( 8+r)*64 + l];
                acc3[r] += r0[(12+r)*64 + l] + r1[(12+r)*64 + l] + r2[(12+r)*64 + l];
            }
            #pragma unroll
            for (int r = 0; r < 4; r++){
                const int m = m0 + q4*4 + r;
                float gi = acc0[r] + bi;
                float gf = acc1[r] + bf_;
                float gg = acc2[r] + bg;
                float go = acc3[r] + bo;
                float co = cbuf[(size_t)m*Hn + u];
                float cn = sigmoidf_(gf)*co + sigmoidf_(gi)*tanhf(gg);
                float hv = sigmoidf_(go)*tanhf(cn);
                cbuf[(size_t)m*Hn + u] = cn;
                unsigned short hb = f2bf(hv);
                const int lanep = (q4*4 + r) + lsh;
                st_cg16(An + (((size_t)rg*KCD + 32 + (u >> 5))*64 + lanep)*8 + (u & 7), hb);
                st_cg16(hplain + (size_t)m*Hn + u, hb);
            }
        }
        bstep++; gbar2(bar, g, rep, bstep);
    }

    // final pred: out[:, Tn-1] = fc(h_{Tn-1})
    if (x == 0 && w >= 6){
        const int b = y*2 + (w & 1);
        float p = fcdot(hplain, fcW, b, l);
        if (l == 0) out[b*Tn + (Tn - 1)] = p + fcb[0];
    }
}

extern "C" void kernel_launch(void* const* d_in, const int* in_sizes, int n_in,
                              void* d_out, int out_size, void* d_ws, size_t ws_size,
                              hipStream_t stream){
    const float* src  = (const float*)d_in[0];
    const float* eWih = (const float*)d_in[1];
    const float* eWhh = (const float*)d_in[2];
    const float* ebih = (const float*)d_in[3];
    const float* ebhh = (const float*)d_in[4];
    const float* dWih = (const float*)d_in[5];
    const float* dWhh = (const float*)d_in[6];
    const float* dbih = (const float*)d_in[7];
    const float* dbhh = (const float*)d_in[8];
    const float* attnW= (const float*)d_in[9];
    const float* fcW  = (const float*)d_in[10];
    const float* fcb  = (const float*)d_in[11];
    float* out = (float*)d_out;

    char* base = (char*)d_ws;
    auto alloc = [&](size_t bytes){ void* p = base; base += (bytes + 255) & ~255ull; return p; };
    unsigned short* Wencf = (unsigned short*)alloc((size_t)256*KCE*512*2);
    float*          benc  = (float*)alloc(G4*4);
    unsigned short* Wdecf = (unsigned short*)alloc((size_t)256*KCD*512*2);
    float*          bdec  = (float*)alloc(G4*4);
    unsigned short* Wattf = (unsigned short*)alloc((size_t)64*KCQ*512*2);
    unsigned short* srcf  = (unsigned short*)alloc((size_t)Sn*8*2*512*2);
    unsigned short* enco  = (unsigned short*)alloc((size_t)Bn*Sn*Hn*2);
    unsigned short* hf0   = (unsigned short*)alloc((size_t)8*32*512*2);
    unsigned short* hf1   = (unsigned short*)alloc((size_t)8*32*512*2);
    float*          cbuf  = (float*)alloc((size_t)Bn*Hn*4);
    unsigned short* A0f   = (unsigned short*)alloc((size_t)8*KCD*512*2);
    unsigned short* A1f   = (unsigned short*)alloc((size_t)8*KCD*512*2);
    unsigned short* qbf   = (unsigned short*)alloc((size_t)Bn*Hn*2);
    unsigned short* hplain= (unsigned short*)alloc((size_t)Bn*Hn*2);
    float*          pctx  = (float*)alloc((size_t)2*128*1024*4);
    float*          pml   = (float*)alloc((size_t)2*128*2*4);
    unsigned*       bars  = (unsigned*)alloc(2048*4);

    conv_srcf<<<2048, 256, 0, stream>>>(src, srcf);
    pack_encf<<<4096, 256, 0, stream>>>(eWih, eWhh, ebih, ebhh, Wencf, benc);
    pack_decf<<<8192, 256, 0, stream>>>(dWih, dWhh, dbih, dbhh, Wdecf, bdec);
    pack_attnf<<<1024, 256, 0, stream>>>(attnW, Wattf);
    init_ws<<<1040, 256, 0, stream>>>(hf0, cbuf, A0f, A1f, bars);

    enc_loop<<<NBLK, 256, 0, stream>>>(srcf, Wencf, benc, cbuf, hf0, hf1,
                                       enco, A0f, bars + 0);
    dec_loop<<<NBLK, 512, 0, stream>>>(A0f, A1f, Wdecf, bdec, cbuf, Wattf,
                                       qbf, enco, hplain, pctx, pml,
                                       fcW, fcb, out, bars + 1024);
}